// Round 1
// baseline (622.770 us; speedup 1.0000x reference)
//
#include <hip/hip_runtime.h>
#include <hip/hip_fp16.h>
#include <math.h>

typedef _Float16 f16;
typedef _Float16 half8_t __attribute__((ext_vector_type(8)));
typedef _Float16 half4_t __attribute__((ext_vector_type(4)));
typedef float    float4_t __attribute__((ext_vector_type(4)));

#define TILE_M 128
#define TILE_N 128
#define TILE_K 32

// C[m,n] = sum_k A[m,k] * Bw[n,k] + bias[n]   (i.e. A @ W^T + b, W row-major NxK)
// TA = float (raw inputs) or f16 (attention output); TC = f16 (proj) or float (final)
template <typename TA, typename TC>
__global__ __launch_bounds__(256) void gemm_bias_kernel(
    const TA* __restrict__ A, const float* __restrict__ Bw,
    const float* __restrict__ bias, TC* __restrict__ C,
    int M, int K, int N)
{
    __shared__ f16 As[TILE_M][TILE_K];
    __shared__ f16 Bs[TILE_N][TILE_K];

    const int tid  = threadIdx.x;
    const int lane = tid & 63;
    const int wave = tid >> 6;
    const int wm = (wave >> 1) * 64;   // wave row offset within 128-tile
    const int wn = (wave & 1) * 64;    // wave col offset
    const int row0 = blockIdx.x * TILE_M;
    const int col0 = blockIdx.y * TILE_N;

    float4_t acc[4][4];
#pragma unroll
    for (int i = 0; i < 4; ++i)
#pragma unroll
        for (int j = 0; j < 4; ++j)
            acc[i][j] = (float4_t){0.f, 0.f, 0.f, 0.f};

    const int lrow = lane & 15;        // A/B fragment row (m or n)
    const int koff = (lane >> 4) * 8;  // A/B fragment k offset (8 halves per lane)

    for (int kt = 0; kt < K; kt += TILE_K) {
        // Stage A-tile (128x32) and B-tile (128x32) into LDS as f16.
        // 1024 groups of 4 elements each; 256 threads x 4 iterations.
#pragma unroll
        for (int it = 0; it < 4; ++it) {
            const int g = tid + it * 256;     // 0..1023
            const int r = g >> 3;             // 0..127
            const int c = (g & 7) << 2;       // 0,4,...,28
            if constexpr (sizeof(TA) == 4) {
                const float4_t va = *(const float4_t*)((const float*)A + (size_t)(row0 + r) * K + kt + c);
                half4_t h;
                h[0] = (f16)va[0]; h[1] = (f16)va[1]; h[2] = (f16)va[2]; h[3] = (f16)va[3];
                *(half4_t*)&As[r][c] = h;
            } else {
                *(half4_t*)&As[r][c] = *(const half4_t*)((const f16*)A + (size_t)(row0 + r) * K + kt + c);
            }
            const float4_t vb = *(const float4_t*)(Bw + (size_t)(col0 + r) * K + kt + c);
            half4_t hb;
            hb[0] = (f16)vb[0]; hb[1] = (f16)vb[1]; hb[2] = (f16)vb[2]; hb[3] = (f16)vb[3];
            *(half4_t*)&Bs[r][c] = hb;
        }
        __syncthreads();

        half8_t afrag[4], bfrag[4];
#pragma unroll
        for (int i = 0; i < 4; ++i)
            afrag[i] = *(const half8_t*)&As[wm + i * 16 + lrow][koff];
#pragma unroll
        for (int j = 0; j < 4; ++j)
            bfrag[j] = *(const half8_t*)&Bs[wn + j * 16 + lrow][koff];
#pragma unroll
        for (int i = 0; i < 4; ++i)
#pragma unroll
            for (int j = 0; j < 4; ++j)
                acc[i][j] = __builtin_amdgcn_mfma_f32_16x16x32_f16(afrag[i], bfrag[j], acc[i][j], 0, 0, 0);
        __syncthreads();
    }

    // Epilogue: C/D layout col = lane&15, row = (lane>>4)*4 + reg
    const int ccol  = lane & 15;
    const int rbase = (lane >> 4) * 4;
#pragma unroll
    for (int j = 0; j < 4; ++j) {
        const int gcol = col0 + wn + j * 16 + ccol;
        const float bv = bias[gcol];
#pragma unroll
        for (int i = 0; i < 4; ++i) {
#pragma unroll
            for (int r = 0; r < 4; ++r) {
                const int grow = row0 + wm + i * 16 + rbase + r;
                const float v = acc[i][j][r] + bv;
                C[(size_t)grow * N + gcol] = (TC)v;
            }
        }
    }
}

// One wave per (b,s) position. Q/K/V for the position are 16x64 (h-major) f16.
// logits[d][e] = sum_h Q[h][d]*K[h][e] / 8 ; softmax over e ; out[d][h] = sum_e p[d][e]*V[h][e]
// lane = d, so each lane owns a full softmax row (no cross-lane reduction).
// Output written in permuted layout out[((b*64+d)*2048+s)*16 + h] so the final
// linear reads a plain contiguous (16384 x 1024) f16 matrix.
__global__ __launch_bounds__(256) void attn_kernel(
    const f16* __restrict__ pq, const f16* __restrict__ pk,
    const f16* __restrict__ pv, f16* __restrict__ outp)
{
    __shared__ float Ks[4][16][64];
    __shared__ float Vs[4][16][64];
    const int lane = threadIdx.x & 63;
    const int wave = threadIdx.x >> 6;
    const int p = blockIdx.x * 4 + wave;
    const int b = p >> 11;      // /2048
    const int s = p & 2047;
    const f16* qp = pq + (size_t)p * 1024;
    const f16* kp = pk + (size_t)p * 1024;
    const f16* vp = pv + (size_t)p * 1024;

    // Stage K,V into LDS as f32 (each lane converts 16 contiguous halves)
    {
        float* kd = &Ks[wave][0][0];
        float* vd = &Vs[wave][0][0];
        const half8_t k0 = *(const half8_t*)(kp + lane * 16);
        const half8_t k1 = *(const half8_t*)(kp + lane * 16 + 8);
        const half8_t v0 = *(const half8_t*)(vp + lane * 16);
        const half8_t v1 = *(const half8_t*)(vp + lane * 16 + 8);
#pragma unroll
        for (int i = 0; i < 8; ++i) {
            kd[lane * 16 + i]     = (float)k0[i];
            kd[lane * 16 + 8 + i] = (float)k1[i];
            vd[lane * 16 + i]     = (float)v0[i];
            vd[lane * 16 + 8 + i] = (float)v1[i];
        }
    }
    float qr[16];
#pragma unroll
    for (int h = 0; h < 16; ++h) qr[h] = (float)qp[h * 64 + lane];
    __syncthreads();

    float a[64];
#pragma unroll
    for (int e = 0; e < 64; ++e) a[e] = 0.f;
#pragma unroll
    for (int h = 0; h < 16; ++h) {
        const float qh = qr[h];
        const float4_t* krow = (const float4_t*)&Ks[wave][h][0];
#pragma unroll
        for (int e4 = 0; e4 < 16; ++e4) {
            const float4_t kv = krow[e4];
            a[e4 * 4 + 0] += qh * kv[0];
            a[e4 * 4 + 1] += qh * kv[1];
            a[e4 * 4 + 2] += qh * kv[2];
            a[e4 * 4 + 3] += qh * kv[3];
        }
    }
    // softmax over e, scale logits by 1/sqrt(64)=0.125 (fold scale into exp arg)
    float m = a[0];
#pragma unroll
    for (int e = 1; e < 64; ++e) m = fmaxf(m, a[e]);
    float sum = 0.f;
#pragma unroll
    for (int e = 0; e < 64; ++e) {
        const float t = __expf((a[e] - m) * 0.125f);
        a[e] = t;
        sum += t;
    }
    const float inv = 1.f / sum;

    half8_t o0, o1;
#pragma unroll
    for (int h = 0; h < 16; ++h) {
        const float4_t* vrow = (const float4_t*)&Vs[wave][h][0];
        float o = 0.f;
#pragma unroll
        for (int e4 = 0; e4 < 16; ++e4) {
            const float4_t vv = vrow[e4];
            o += a[e4 * 4 + 0] * vv[0] + a[e4 * 4 + 1] * vv[1]
               + a[e4 * 4 + 2] * vv[2] + a[e4 * 4 + 3] * vv[3];
        }
        const f16 hv = (f16)(o * inv);
        if (h < 8) o0[h] = hv; else o1[h - 8] = hv;
    }
    f16* dst = outp + ((size_t)(b * 64 + lane) * 2048 + s) * 16;
    *(half8_t*)dst       = o0;
    *(half8_t*)(dst + 8) = o1;
}

extern "C" void kernel_launch(void* const* d_in, const int* in_sizes, int n_in,
                              void* d_out, int out_size, void* d_ws, size_t ws_size,
                              hipStream_t stream)
{
    const float* q    = (const float*)d_in[0];
    const float* k    = (const float*)d_in[1];
    const float* v    = (const float*)d_in[2];
    const float* W    = (const float*)d_in[3];
    const float* bias = (const float*)d_in[4];
    float* out = (float*)d_out;

    const int M = 16384, K = 1024, N = 1024;
    const size_t elems = (size_t)M * N;  // 16M

    // ws: projq (32MB f16) + attn_out (32MB f16)
    f16* projq = (f16*)d_ws;
    f16* attn  = projq + elems;
    // projk/projv live inside d_out (64MB fp32 = 2 x 32MB f16); consumed by
    // attn_kernel before the final GEMM overwrites d_out.
    f16* projk = (f16*)d_out;
    f16* projv = projk + elems;

    dim3 grid(M / TILE_M, N / TILE_N);  // 128 x 8
    gemm_bias_kernel<float, f16><<<grid, 256, 0, stream>>>(q, W, bias, projq, M, K, N);
    gemm_bias_kernel<float, f16><<<grid, 256, 0, stream>>>(k, W, bias, projk, M, K, N);
    gemm_bias_kernel<float, f16><<<grid, 256, 0, stream>>>(v, W, bias, projv, M, K, N);
    attn_kernel<<<M / 4, 256, 0, stream>>>(projq, projk, projv, attn);
    gemm_bias_kernel<f16, float><<<grid, 256, 0, stream>>>(attn, W, bias, out, M, K, N);
}

// Round 3
// 495.680 us; speedup vs baseline: 1.2564x; 1.2564x over previous
//
#include <hip/hip_runtime.h>
#include <hip/hip_fp16.h>
#include <math.h>

typedef _Float16 f16;
typedef _Float16 half8_t __attribute__((ext_vector_type(8)));
typedef _Float16 half2_t __attribute__((ext_vector_type(2)));
typedef __fp16   fp16x2  __attribute__((ext_vector_type(2)));
typedef float    float4_t __attribute__((ext_vector_type(4)));

// Converted weights (f16), written once per call by convert_w_kernel.
__device__ f16 Wh[1024 * 1024];

__device__ __forceinline__ void gl_lds16(const void* g, void* l) {
    __builtin_amdgcn_global_load_lds(
        (const __attribute__((address_space(1))) void*)g,
        (__attribute__((address_space(3))) void*)l,
        16, 0, 0);
}

__device__ __forceinline__ half2_t pkrtz(float a, float b) {
    fp16x2 r = __builtin_amdgcn_cvt_pkrtz(a, b);
    return __builtin_bit_cast(half2_t, r);
}

__device__ __forceinline__ float fdot2(half2_t a, half2_t b, float c) {
    return __builtin_amdgcn_fdot2(__builtin_bit_cast(fp16x2, a),
                                  __builtin_bit_cast(fp16x2, b), c, false);
}

__device__ __forceinline__ half8_t cvt8(float4_t lo, float4_t hi) {
    half2_t p0 = pkrtz(lo[0], lo[1]);
    half2_t p1 = pkrtz(lo[2], lo[3]);
    half2_t p2 = pkrtz(hi[0], hi[1]);
    half2_t p3 = pkrtz(hi[2], hi[3]);
    half8_t r;
    r[0] = p0[0]; r[1] = p0[1]; r[2] = p1[0]; r[3] = p1[1];
    r[4] = p2[0]; r[5] = p2[1]; r[6] = p3[0]; r[7] = p3[1];
    return r;
}

__global__ __launch_bounds__(256) void convert_w_kernel(const float* __restrict__ W) {
    const int i = (blockIdx.x * 256 + threadIdx.x) * 8;
    const float4_t a = *(const float4_t*)(W + i);
    const float4_t b = *(const float4_t*)(W + i + 4);
    half8_t h;  // RTN conversion (accuracy; this kernel is cold)
#pragma unroll
    for (int t = 0; t < 4; ++t) h[t] = (f16)a[t];
#pragma unroll
    for (int t = 0; t < 4; ++t) h[4 + t] = (f16)b[t];
    *(half8_t*)(Wh + i) = h;
}

// C[m,n] = sum_k A[m,k] * W[n,k] + bias[n].  M=16384, K=N=1024.
// B-tile staged from Wh (f16) via global_load_lds; A-tile staged as raw f32
// (TA=float) via global_load_lds and converted to f16 at fragment-read time,
// or staged f16 directly (TA=f16). LDS chunks XOR-swizzled (16B granularity)
// so fragment reads are <=2-way bank-aliased.
template <typename TA, typename TC>
__global__ __launch_bounds__(256) void gemm_kernel(
    const TA* __restrict__ A, const float* __restrict__ bias,
    TC* __restrict__ C)
{
    constexpr int K = 1024, N = 1024;
    constexpr bool AF32 = (sizeof(TA) == 4);
    __shared__ __align__(16) char smem[(AF32 ? 16384 : 8192) + 8192];
    float* Asf = (float*)smem;
    f16*   Ash = (f16*)smem;
    f16*   Bsh = (f16*)(smem + (AF32 ? 16384 : 8192));

    const int tid  = threadIdx.x;
    const int lane = tid & 63;
    const int wave = tid >> 6;
    const int wm = (wave >> 1) << 6;
    const int wn = (wave & 1) << 6;
    const int row0 = blockIdx.x * 128;
    const int col0 = blockIdx.y * 128;
    const int lrow = lane & 15;
    const int kq   = lane >> 4;  // 0..3, fragment k-chunk

    float4_t acc[4][4];
#pragma unroll
    for (int i = 0; i < 4; ++i)
#pragma unroll
        for (int j = 0; j < 4; ++j)
            acc[i][j] = (float4_t){0.f, 0.f, 0.f, 0.f};

    for (int kt = 0; kt < K; kt += 32) {
        // Stage B (Wh, f16): 128 rows x 32 halves = 512 x 16B chunks.
        // LDS slot s at row r holds logical chunk s ^ ((r>>1)&3).
#pragma unroll
        for (int it = 0; it < 2; ++it) {
            const int ch = tid + it * 256;
            const int r = ch >> 2, s = ch & 3;
            const f16* src = Wh + (size_t)(col0 + r) * K + kt + ((s ^ ((r >> 1) & 3)) << 3);
            gl_lds16(src, Bsh + ch * 8);
        }
        if constexpr (AF32) {
            // A f32: 128 rows x 32 floats = 1024 x 16B chunks; slot s holds s ^ (r&7).
#pragma unroll
            for (int it = 0; it < 4; ++it) {
                const int ch = tid + it * 256;
                const int r = ch >> 3, s = ch & 7;
                const float* src = (const float*)A + (size_t)(row0 + r) * K + kt + ((s ^ (r & 7)) << 2);
                gl_lds16(src, Asf + ch * 4);
            }
        } else {
#pragma unroll
            for (int it = 0; it < 2; ++it) {
                const int ch = tid + it * 256;
                const int r = ch >> 2, s = ch & 3;
                const f16* src = (const f16*)A + (size_t)(row0 + r) * K + kt + ((s ^ ((r >> 1) & 3)) << 3);
                gl_lds16(src, Ash + ch * 8);
            }
        }
        __syncthreads();

        half8_t af[4], bf[4];
#pragma unroll
        for (int i = 0; i < 4; ++i) {
            const int m = wm + i * 16 + lrow;
            if constexpr (AF32) {
                const int c0 = kq * 2;
                const float4_t lo = *(const float4_t*)(Asf + m * 32 + ((c0 ^ (m & 7)) << 2));
                const float4_t hi = *(const float4_t*)(Asf + m * 32 + (((c0 + 1) ^ (m & 7)) << 2));
                af[i] = cvt8(lo, hi);
            } else {
                af[i] = *(const half8_t*)(Ash + m * 32 + ((kq ^ ((m >> 1) & 3)) << 3));
            }
        }
#pragma unroll
        for (int j = 0; j < 4; ++j) {
            const int n = wn + j * 16 + lrow;
            bf[j] = *(const half8_t*)(Bsh + n * 32 + ((kq ^ ((n >> 1) & 3)) << 3));
        }
#pragma unroll
        for (int i = 0; i < 4; ++i)
#pragma unroll
            for (int j = 0; j < 4; ++j)
                acc[i][j] = __builtin_amdgcn_mfma_f32_16x16x32_f16(af[i], bf[j], acc[i][j], 0, 0, 0);
        __syncthreads();
    }

    // Epilogue (proven in round 1): C/D layout col=lane&15, row=(lane>>4)*4+reg
    const int ccol  = lane & 15;
    const int rbase = (lane >> 4) << 2;
#pragma unroll
    for (int j = 0; j < 4; ++j) {
        const int gcol = col0 + wn + j * 16 + ccol;
        const float bv = bias[gcol];
#pragma unroll
        for (int i = 0; i < 4; ++i) {
#pragma unroll
            for (int r = 0; r < 4; ++r) {
                const int grow = row0 + wm + i * 16 + rbase + r;
                C[(size_t)grow * N + gcol] = (TC)(acc[i][j][r] + bv);
            }
        }
    }
}

// One wave per (b,s). lane = d owns a full softmax row (no cross-lane ops).
// K staged transposed [e][h] (rows padded to 24 halves = 48B, 16B-aligned),
// V staged straight [h][e] (rows padded to 72 halves = 144B). Both f16.
// QK and PV use v_dot2_f32_f16 with f32 accumulation.
__global__ __launch_bounds__(256) void attn_kernel(
    const f16* __restrict__ pq, const f16* __restrict__ pk,
    const f16* __restrict__ pv, f16* __restrict__ outp)
{
    __shared__ __align__(16) f16 Ks[4][64][24];
    __shared__ __align__(16) f16 Vs[4][16][72];
    const int lane = threadIdx.x & 63;
    const int wave = threadIdx.x >> 6;
    const int p = blockIdx.x * 4 + wave;
    const int b = p >> 11;   // / 2048
    const int s = p & 2047;
    const f16* qptr = pq + (size_t)p * 1024;
    const f16* kptr = pk + (size_t)p * 1024;
    const f16* vptr = pv + (size_t)p * 1024;

    // Stage: lane holds global halves [lane*16, lane*16+16) = h = lane>>2,
    // e in [(lane&3)*16, +16).
    {
        const int h  = lane >> 2;
        const int e0 = (lane & 3) << 4;
        const half8_t k0 = *(const half8_t*)(kptr + lane * 16);
        const half8_t k1 = *(const half8_t*)(kptr + lane * 16 + 8);
#pragma unroll
        for (int t = 0; t < 8; ++t) {
            Ks[wave][e0 + t][h]     = k0[t];
            Ks[wave][e0 + 8 + t][h] = k1[t];
        }
        const half8_t v0 = *(const half8_t*)(vptr + lane * 16);
        const half8_t v1 = *(const half8_t*)(vptr + lane * 16 + 8);
        *(half8_t*)&Vs[wave][h][e0]     = v0;
        *(half8_t*)&Vs[wave][h][e0 + 8] = v1;
    }
    // Q pairs: qp2[h2] = (Q[2h2][d], Q[2h2+1][d]), d = lane (h-major strided loads)
    half2_t qp2[8];
#pragma unroll
    for (int h2 = 0; h2 < 8; ++h2) {
        half2_t t;
        t[0] = qptr[(2 * h2) * 64 + lane];
        t[1] = qptr[(2 * h2 + 1) * 64 + lane];
        qp2[h2] = t;
    }
    __syncthreads();

    // logits[d=lane][e] = sum_h Q[h][d] K[h][e]
    float a[64];
#pragma unroll
    for (int e = 0; e < 64; ++e) {
        const half8_t* kr = (const half8_t*)&Ks[wave][e][0];
        const half8_t ka = kr[0];
        const half8_t kb = kr[1];
        float acc = 0.f;
#pragma unroll
        for (int t = 0; t < 4; ++t) {
            half2_t k2a; k2a[0] = ka[2 * t]; k2a[1] = ka[2 * t + 1];
            half2_t k2b; k2b[0] = kb[2 * t]; k2b[1] = kb[2 * t + 1];
            acc = fdot2(qp2[t], k2a, acc);
            acc = fdot2(qp2[4 + t], k2b, acc);
        }
        a[e] = acc;
    }

    // softmax over e (scale 1/sqrt(64) folded into exp arg)
    float m = a[0];
#pragma unroll
    for (int e = 1; e < 64; ++e) m = fmaxf(m, a[e]);
    float sum = 0.f;
#pragma unroll
    for (int e = 0; e < 64; ++e) {
        const float t = __expf((a[e] - m) * 0.125f);
        a[e] = t;
        sum += t;
    }
    const float inv = 1.f / sum;

    half2_t pk2[32];
#pragma unroll
    for (int e2 = 0; e2 < 32; ++e2)
        pk2[e2] = pkrtz(a[2 * e2], a[2 * e2 + 1]);

    // out[d][h] = inv * sum_e p[d][e] V[h][e]
    float o[16];
#pragma unroll
    for (int h = 0; h < 16; ++h) {
        const half8_t* vr = (const half8_t*)&Vs[wave][h][0];
        float acc = 0.f;
#pragma unroll
        for (int q8 = 0; q8 < 8; ++q8) {
            const half8_t vv = vr[q8];
#pragma unroll
            for (int t = 0; t < 4; ++t) {
                half2_t v2; v2[0] = vv[2 * t]; v2[1] = vv[2 * t + 1];
                acc = fdot2(pk2[q8 * 4 + t], v2, acc);
            }
        }
        o[h] = acc;
    }

    half8_t o0, o1;
#pragma unroll
    for (int h = 0; h < 8; ++h) o0[h] = (f16)(o[h] * inv);
#pragma unroll
    for (int h = 0; h < 8; ++h) o1[h] = (f16)(o[8 + h] * inv);
    // permuted output layout (B, D, S, H) = final linear's flat row-major input
    f16* dst = outp + ((size_t)(b * 64 + lane) * 2048 + s) * 16;
    *(half8_t*)dst       = o0;
    *(half8_t*)(dst + 8) = o1;
}

extern "C" void kernel_launch(void* const* d_in, const int* in_sizes, int n_in,
                              void* d_out, int out_size, void* d_ws, size_t ws_size,
                              hipStream_t stream)
{
    const float* q    = (const float*)d_in[0];
    const float* k    = (const float*)d_in[1];
    const float* v    = (const float*)d_in[2];
    const float* W    = (const float*)d_in[3];
    const float* bias = (const float*)d_in[4];
    float* out = (float*)d_out;

    const int M = 16384;
    const size_t elems = (size_t)M * 1024;

    // ws: projq (32MB f16) + attn_out (32MB f16). projk/projv parked inside
    // d_out (64MB fp32), consumed by attn before the final GEMM overwrites it.
    f16* projq = (f16*)d_ws;
    f16* attn  = projq + elems;
    f16* projk = (f16*)d_out;
    f16* projv = projk + elems;

    convert_w_kernel<<<512, 256, 0, stream>>>(W);

    dim3 grid(M / 128, 1024 / 128);  // 128 x 8
    gemm_kernel<float, f16><<<grid, 256, 0, stream>>>(q, bias, projq);
    gemm_kernel<float, f16><<<grid, 256, 0, stream>>>(k, bias, projk);
    gemm_kernel<float, f16><<<grid, 256, 0, stream>>>(v, bias, projv);
    attn_kernel<<<M / 4, 256, 0, stream>>>(projq, projk, projv, attn);
    gemm_kernel<f16, float><<<grid, 256, 0, stream>>>(attn, bias, out);
}